// Round 5
// baseline (4107.380 us; speedup 1.0000x reference)
//
#include <hip/hip_runtime.h>
#include <cstdint>

#define NN 50000
#define DD 128
#define EE 600000

__device__ __forceinline__ float sigmoid_f(float x) {
    return 1.0f / (1.0f + __expf(-x));
}
__device__ __forceinline__ float tanh_f(float x) {
    float e = __expf(-2.0f * fabsf(x));
    float t = (1.0f - e) / (1.0f + e);
    return copysignf(t, x);
}

// ---- weight packing: wpk[k][jg(16)][gate(6)][jj(8)] ----------------------
// Per (k, wave=jg): 48 contiguous floats, identical across the wave's lanes.
__global__ __launch_bounds__(256) void pack_w_kernel(const float* __restrict__ wx,
                                                     const float* __restrict__ wh,
                                                     float* __restrict__ wpk) {
    int idx = blockIdx.x * 256 + threadIdx.x;
    if (idx >= 128 * 768) return;
    int k = idx / 768;
    int rem = idx - k * 768;
    int jg = rem / 48;
    int g = (rem % 48) >> 3;
    int jj = rem & 7;
    int c = jg * 8 + jj;
    float v = (g < 3) ? wx[(g * 128 + c) * 128 + k]
                      : wh[((g - 3) * 128 + c) * 128 + k];
    wpk[idx] = v;
}

// ---- CSR build (all 4 adjacencies batched) -------------------------------

__global__ __launch_bounds__(256) void hist_kernel(const int* __restrict__ rows,
                                                   int* __restrict__ cnt4) {
    int e = blockIdx.x * 256 + threadIdx.x;
    if (e >= EE) return;
    int k = blockIdx.y;
    atomicAdd(&cnt4[k * NN + rows[(size_t)k * EE + e]], 1);
}

__global__ __launch_bounds__(1024) void scan_kernel(const int* __restrict__ cnt4,
                                                    int* __restrict__ row_ptr4,
                                                    int* __restrict__ cursor4) {
    __shared__ int buf[1024];
    const int kadj = blockIdx.x;
    const int* cnt = cnt4 + kadj * NN;
    int* row_ptr = row_ptr4 + kadj * (NN + 1);
    int* cursor = cursor4 + kadj * NN;
    const int tid = threadIdx.x;
    const int CH = (NN + 1023) / 1024;  // 49
    const int base = tid * CH;
    int s = 0;
    #pragma unroll
    for (int i = 0; i < CH; ++i) {
        int idx = base + i;
        if (idx < NN) s += cnt[idx];
    }
    buf[tid] = s;
    __syncthreads();
    for (int d = 1; d < 1024; d <<= 1) {
        int t = (tid >= d) ? buf[tid - d] : 0;
        __syncthreads();
        buf[tid] += t;
        __syncthreads();
    }
    int run = buf[tid] - s;
    #pragma unroll
    for (int i = 0; i < CH; ++i) {
        int idx = base + i;
        if (idx < NN) {
            row_ptr[idx] = run;
            cursor[idx] = run;
            run += cnt[idx];
        }
    }
    if (tid == 0) row_ptr[NN] = EE;
}

__global__ __launch_bounds__(256) void scatter_kernel(const int* __restrict__ rows,
                                                      const int* __restrict__ cols,
                                                      const float* __restrict__ vals,
                                                      int* __restrict__ cursor4,
                                                      int2* __restrict__ epair4) {
    int e = blockIdx.x * 256 + threadIdx.x;
    if (e >= EE) return;
    int k = blockIdx.y;
    size_t off = (size_t)k * EE + e;
    int r = rows[off];
    int pos = atomicAdd(&cursor4[k * NN + r], 1);
    int2 p;
    p.x = cols[off];
    p.y = __float_as_int(vals[off]);
    epair4[(size_t)k * EE + pos] = p;
}

// ---- SpMM gather: res[r] = relu(sum val*x[col]) --------------------------
__global__ __launch_bounds__(256) void gather_kernel(const float* __restrict__ x,
                                                     const int* __restrict__ row_ptr,
                                                     const int2* __restrict__ epair,
                                                     float* __restrict__ res) {
    const int tid = threadIdx.x;
    const int row = blockIdx.x * 8 + (tid >> 5);
    const int d0 = (tid & 31) * 4;
    const int start = row_ptr[row];
    const int end = row_ptr[row + 1];
    float4 a0 = make_float4(0.f, 0.f, 0.f, 0.f);
    float4 a1 = a0, a2 = a0, a3 = a0;
    int e = start;
    for (; e + 3 < end; e += 4) {
        int2 p0 = epair[e], p1 = epair[e + 1], p2 = epair[e + 2], p3 = epair[e + 3];
        float4 x0 = *reinterpret_cast<const float4*>(x + (size_t)p0.x * DD + d0);
        float4 x1 = *reinterpret_cast<const float4*>(x + (size_t)p1.x * DD + d0);
        float4 x2 = *reinterpret_cast<const float4*>(x + (size_t)p2.x * DD + d0);
        float4 x3 = *reinterpret_cast<const float4*>(x + (size_t)p3.x * DD + d0);
        float v0 = __int_as_float(p0.y), v1 = __int_as_float(p1.y);
        float v2 = __int_as_float(p2.y), v3 = __int_as_float(p3.y);
        a0.x += v0 * x0.x; a0.y += v0 * x0.y; a0.z += v0 * x0.z; a0.w += v0 * x0.w;
        a1.x += v1 * x1.x; a1.y += v1 * x1.y; a1.z += v1 * x1.z; a1.w += v1 * x1.w;
        a2.x += v2 * x2.x; a2.y += v2 * x2.y; a2.z += v2 * x2.z; a2.w += v2 * x2.w;
        a3.x += v3 * x3.x; a3.y += v3 * x3.y; a3.z += v3 * x3.z; a3.w += v3 * x3.w;
    }
    for (; e < end; ++e) {
        int2 p0 = epair[e];
        float v0 = __int_as_float(p0.y);
        float4 x0 = *reinterpret_cast<const float4*>(x + (size_t)p0.x * DD + d0);
        a0.x += v0 * x0.x; a0.y += v0 * x0.y; a0.z += v0 * x0.z; a0.w += v0 * x0.w;
    }
    float4 o;
    o.x = fmaxf((a0.x + a1.x) + (a2.x + a3.x), 0.f);
    o.y = fmaxf((a0.y + a1.y) + (a2.y + a3.y), 0.f);
    o.z = fmaxf((a0.z + a1.z) + (a2.z + a3.z), 0.f);
    o.w = fmaxf((a0.w + a1.w) + (a2.w + a3.w), 0.f);
    *reinterpret_cast<float4*>(res + (size_t)row * DD + d0) = o;
}

// ---- Fused dual-GEMM + GRU ------------------------------------------------
// Block: 64 rows (lanes) x 128 cols (16 waves x 8 j). Inputs transposed in
// LDS (period-4 XOR swizzle, 2-way aliasing = free). Weights: wave-uniform
// VMEM float4 loads, explicit depth-2 ping-pong prefetch in VGPRs.
#define FMA8(acc, s, q0, q1)                                              \
    acc[0] += s * q0.x; acc[1] += s * q0.y; acc[2] += s * q0.z;           \
    acc[3] += s * q0.w; acc[4] += s * q1.x; acc[5] += s * q1.y;           \
    acc[6] += s * q1.z; acc[7] += s * q1.w;

template <bool FIRST>
__global__ __launch_bounds__(1024) void gru_step_kernel(const float* __restrict__ res,
                                                        float* __restrict__ h,
                                                        const float* __restrict__ wpk,
                                                        const float* __restrict__ bx,
                                                        const float* __restrict__ bh) {
    __shared__ float s_a[128 * 64];                 // relu(res) transposed, 32 KB
    __shared__ float s_b[FIRST ? 64 : 128 * 64];    // h transposed

    const int tid = threadIdx.x;
    const int row0 = blockIdx.x * 64;

    // stage + transpose; swizzled write s[(k<<6) | (rl ^ (k>>2))]
    #pragma unroll
    for (int p = 0; p < 2; ++p) {
        int idx = p * 1024 + tid;
        int rl = idx >> 5;
        int kq = (idx & 31) * 4;
        int grow = row0 + rl;
        float4 rv = make_float4(0.f, 0.f, 0.f, 0.f);
        float4 hv = make_float4(0.f, 0.f, 0.f, 0.f);
        if (grow < NN) {
            rv = *reinterpret_cast<const float4*>(res + (size_t)grow * DD + kq);
            if (!FIRST) hv = *reinterpret_cast<const float4*>(h + (size_t)grow * DD + kq);
        }
        float rr[4] = {rv.x, rv.y, rv.z, rv.w};
        float hh[4] = {hv.x, hv.y, hv.z, hv.w};
        int g = idx & 31;                  // == (kq+i)>>2 for i in 0..3
        int swb = (rl ^ g);
        #pragma unroll
        for (int i = 0; i < 4; ++i) {
            int sw = ((kq + i) << 6) | swb;
            s_a[sw] = rr[i];
            if (!FIRST) s_b[sw] = hh[i];
        }
    }

    const int lane = tid & 63;
    const int wave = tid >> 6;                        // 0..15
    const int jbase = wave * 8;
    const float* __restrict__ wbase = wpk + wave * 48;  // wave-uniform

    float sr[8], si[8], sn[8], hn[8];
    {
        float4 x0 = *reinterpret_cast<const float4*>(bx + jbase);
        float4 x1 = *reinterpret_cast<const float4*>(bx + jbase + 4);
        float4 i0 = *reinterpret_cast<const float4*>(bx + DD + jbase);
        float4 i1 = *reinterpret_cast<const float4*>(bx + DD + jbase + 4);
        float4 n0 = *reinterpret_cast<const float4*>(bx + 2 * DD + jbase);
        float4 n1 = *reinterpret_cast<const float4*>(bx + 2 * DD + jbase + 4);
        float4 hr0 = *reinterpret_cast<const float4*>(bh + jbase);
        float4 hr1 = *reinterpret_cast<const float4*>(bh + jbase + 4);
        float4 hi0 = *reinterpret_cast<const float4*>(bh + DD + jbase);
        float4 hi1 = *reinterpret_cast<const float4*>(bh + DD + jbase + 4);
        float4 hn0 = *reinterpret_cast<const float4*>(bh + 2 * DD + jbase);
        float4 hn1 = *reinterpret_cast<const float4*>(bh + 2 * DD + jbase + 4);
        sr[0] = x0.x + hr0.x; sr[1] = x0.y + hr0.y; sr[2] = x0.z + hr0.z; sr[3] = x0.w + hr0.w;
        sr[4] = x1.x + hr1.x; sr[5] = x1.y + hr1.y; sr[6] = x1.z + hr1.z; sr[7] = x1.w + hr1.w;
        si[0] = i0.x + hi0.x; si[1] = i0.y + hi0.y; si[2] = i0.z + hi0.z; si[3] = i0.w + hi0.w;
        si[4] = i1.x + hi1.x; si[5] = i1.y + hi1.y; si[6] = i1.z + hi1.z; si[7] = i1.w + hi1.w;
        sn[0] = n0.x; sn[1] = n0.y; sn[2] = n0.z; sn[3] = n0.w;
        sn[4] = n1.x; sn[5] = n1.y; sn[6] = n1.z; sn[7] = n1.w;
        hn[0] = hn0.x; hn[1] = hn0.y; hn[2] = hn0.z; hn[3] = hn0.w;
        hn[4] = hn1.x; hn[5] = hn1.y; hn[6] = hn1.z; hn[7] = hn1.w;
    }

    constexpr int NW = FIRST ? 6 : 12;   // float4s of weights per k
    float4 wA[NW], wB[NW];
    {
        const float4* q0 = reinterpret_cast<const float4*>(wbase);
        const float4* q1 = reinterpret_cast<const float4*>(wbase + 768);
        #pragma unroll
        for (int t = 0; t < NW; ++t) { wA[t] = q0[t]; wB[t] = q1[t]; }
    }

    __syncthreads();   // the only barrier

    for (int k = 0; k < DD; k += 2) {
        int sw0 = (k << 6) | (lane ^ (k >> 2));
        float a0 = s_a[sw0];
        float a1 = s_a[sw0 + 64];
        float b0 = 0.f, b1 = 0.f;
        if (!FIRST) { b0 = s_b[sw0]; b1 = s_b[sw0 + 64]; }

        // consume wA (k), then refill for k+2 (pad rows 128/129 exist)
        FMA8(sr, a0, wA[0], wA[1]);
        FMA8(si, a0, wA[2], wA[3]);
        FMA8(sn, a0, wA[4], wA[5]);
        if (!FIRST) {
            FMA8(sr, b0, wA[6], wA[7]);
            FMA8(si, b0, wA[8], wA[9]);
            FMA8(hn, b0, wA[10], wA[11]);
        }
        {
            const float4* q = reinterpret_cast<const float4*>(wbase + (size_t)(k + 2) * 768);
            #pragma unroll
            for (int t = 0; t < NW; ++t) wA[t] = q[t];
        }

        // consume wB (k+1), refill for k+3
        FMA8(sr, a1, wB[0], wB[1]);
        FMA8(si, a1, wB[2], wB[3]);
        FMA8(sn, a1, wB[4], wB[5]);
        if (!FIRST) {
            FMA8(sr, b1, wB[6], wB[7]);
            FMA8(si, b1, wB[8], wB[9]);
            FMA8(hn, b1, wB[10], wB[11]);
        }
        {
            const float4* q = reinterpret_cast<const float4*>(wbase + (size_t)(k + 3) * 768);
            #pragma unroll
            for (int t = 0; t < NW; ++t) wB[t] = q[t];
        }
    }

    int row = row0 + lane;
    if (row < NN) {
        float o[8];
        #pragma unroll
        for (int j = 0; j < 8; ++j) {
            int jc = jbase + j;
            float ho = 0.f;
            if (!FIRST) ho = s_b[(jc << 6) | (lane ^ (jc >> 2))];
            float rg = sigmoid_f(sr[j]);
            float ig = sigmoid_f(si[j]);
            float ng = tanh_f(sn[j] + rg * hn[j]);
            o[j] = ng + ig * (ho - ng);
        }
        float* hp = h + (size_t)row * DD + jbase;
        *reinterpret_cast<float4*>(hp) = make_float4(o[0], o[1], o[2], o[3]);
        *reinterpret_cast<float4*>(hp + 4) = make_float4(o[4], o[5], o[6], o[7]);
    }
}

// LayerNorm over D=128, 32 lanes/row, two-pass variance (matches jnp.var)
__global__ __launch_bounds__(256) void ln_kernel(float* __restrict__ h,
                                                 const float* __restrict__ g,
                                                 const float* __restrict__ b) {
    int tid = threadIdx.x;
    int lane = tid & 31;
    int rl = tid >> 5;
    int row = blockIdx.x * 8 + rl;
    if (row >= NN) return;
    float4 v = *reinterpret_cast<const float4*>(h + (size_t)row * DD + lane * 4);
    float s = v.x + v.y + v.z + v.w;
    #pragma unroll
    for (int m = 16; m >= 1; m >>= 1) s += __shfl_xor(s, m, 64);
    float mean = s * (1.0f / DD);
    float dx = v.x - mean, dy = v.y - mean, dz = v.z - mean, dw = v.w - mean;
    float q = dx * dx + dy * dy + dz * dz + dw * dw;
    #pragma unroll
    for (int m = 16; m >= 1; m >>= 1) q += __shfl_xor(q, m, 64);
    float var = q * (1.0f / DD);
    float inv = 1.0f / sqrtf(var + 1e-5f);
    float4 gv = *reinterpret_cast<const float4*>(g + lane * 4);
    float4 bv = *reinterpret_cast<const float4*>(b + lane * 4);
    float4 o;
    o.x = dx * inv * gv.x + bv.x;
    o.y = dy * inv * gv.y + bv.y;
    o.z = dz * inv * gv.z + bv.z;
    o.w = dw * inv * gv.w + bv.w;
    *reinterpret_cast<float4*>(h + (size_t)row * DD + lane * 4) = o;
}

static inline size_t align_up(size_t v, size_t a) { return (v + a - 1) & ~(a - 1); }

extern "C" void kernel_launch(void* const* d_in, const int* in_sizes, int n_in,
                              void* d_out, int out_size, void* d_ws, size_t ws_size,
                              hipStream_t stream) {
    const float* x    = (const float*)d_in[0];
    const float* vals = (const float*)d_in[1];
    const float* wx   = (const float*)d_in[2];
    const float* bx   = (const float*)d_in[3];
    const float* wh   = (const float*)d_in[4];
    const float* bh   = (const float*)d_in[5];
    const float* lng  = (const float*)d_in[6];
    const float* lnb  = (const float*)d_in[7];
    const int* rows   = (const int*)d_in[8];
    const int* cols   = (const int*)d_in[9];

    float* h = (float*)d_out;

    size_t off = 0;
    char* wsb = (char*)d_ws;
    float* res = (float*)(wsb + off);      off = align_up(off + (size_t)NN * DD * 4, 256);
    float* wpk = (float*)(wsb + off);      off = align_up(off + (size_t)130 * 768 * 4, 256);  // 2 pad k-rows
    int* row_ptr4 = (int*)(wsb + off);     off = align_up(off + (size_t)4 * (NN + 1) * 4, 256);
    int* cnt4 = (int*)(wsb + off);         off = align_up(off + (size_t)4 * NN * 4, 256);
    int* cursor4 = (int*)(wsb + off);      off = align_up(off + (size_t)4 * NN * 4, 256);
    int2* epair4 = (int2*)(wsb + off);     off = align_up(off + (size_t)4 * EE * 8, 256);

    (void)in_sizes; (void)n_in; (void)out_size; (void)ws_size;

    pack_w_kernel<<<384, 256, 0, stream>>>(wx, wh, wpk);

    hipMemsetAsync(cnt4, 0, (size_t)4 * NN * sizeof(int), stream);
    dim3 egrid((EE + 255) / 256, 4);
    hist_kernel<<<egrid, 256, 0, stream>>>(rows, cnt4);
    scan_kernel<<<4, 1024, 0, stream>>>(cnt4, row_ptr4, cursor4);
    scatter_kernel<<<egrid, 256, 0, stream>>>(rows, cols, vals, cursor4, epair4);

    const int ggrid = NN / 8;              // 6250
    const int gru_grid = (NN + 63) / 64;   // 782

    for (int s = 0; s < 4; ++s) {
        int k = 3 - s;  // adj_list reversed
        gather_kernel<<<ggrid, 256, 0, stream>>>(
            x, row_ptr4 + (size_t)k * (NN + 1), epair4 + (size_t)k * EE, res);
        if (s == 0)
            gru_step_kernel<true><<<gru_grid, 1024, 0, stream>>>(res, h, wpk, bx, bh);
        else
            gru_step_kernel<false><<<gru_grid, 1024, 0, stream>>>(res, h, wpk, bx, bh);
    }

    ln_kernel<<<(NN + 7) / 8, 256, 0, stream>>>(h, lng, lnb);
}

// Round 7
// 1261.467 us; speedup vs baseline: 3.2560x; 3.2560x over previous
//
#include <hip/hip_runtime.h>
#include <cstdint>

#define NN 50000
#define DD 128
#define EE 600000

__device__ __forceinline__ float sigmoid_f(float x) {
    return 1.0f / (1.0f + __expf(-x));
}
__device__ __forceinline__ float tanh_f(float x) {
    float e = __expf(-2.0f * fabsf(x));
    float t = (1.0f - e) / (1.0f + e);
    return copysignf(t, x);
}

// ---- weight packing: wpk[k][jg(32)][gate(6)][jj(4)] ----------------------
// Per (k, jg): 24 contiguous floats, wave-uniform -> s_load double-buffer.
__global__ __launch_bounds__(256) void pack_w_kernel(const float* __restrict__ wx,
                                                     const float* __restrict__ wh,
                                                     float* __restrict__ wpk) {
    int idx = blockIdx.x * 256 + threadIdx.x;
    if (idx >= 128 * 768) return;
    int k = idx / 768;
    int rem = idx - k * 768;
    int jg = rem / 24;
    int g = (rem % 24) >> 2;
    int jj = rem & 3;
    int c = jg * 4 + jj;
    float v = (g < 3) ? wx[(g * 128 + c) * 128 + k]
                      : wh[((g - 3) * 128 + c) * 128 + k];
    wpk[idx] = v;
}

// ---- CSR build (all 4 adjacencies batched) -------------------------------

__global__ __launch_bounds__(256) void hist_kernel(const int* __restrict__ rows,
                                                   int* __restrict__ cnt4) {
    int e = blockIdx.x * 256 + threadIdx.x;
    if (e >= EE) return;
    int k = blockIdx.y;
    atomicAdd(&cnt4[k * NN + rows[(size_t)k * EE + e]], 1);
}

__global__ __launch_bounds__(1024) void scan_kernel(const int* __restrict__ cnt4,
                                                    int* __restrict__ row_ptr4,
                                                    int* __restrict__ cursor4) {
    __shared__ int buf[1024];
    const int kadj = blockIdx.x;
    const int* cnt = cnt4 + kadj * NN;
    int* row_ptr = row_ptr4 + kadj * (NN + 1);
    int* cursor = cursor4 + kadj * NN;
    const int tid = threadIdx.x;
    const int CH = (NN + 1023) / 1024;  // 49
    const int base = tid * CH;
    int s = 0;
    #pragma unroll
    for (int i = 0; i < CH; ++i) {
        int idx = base + i;
        if (idx < NN) s += cnt[idx];
    }
    buf[tid] = s;
    __syncthreads();
    for (int d = 1; d < 1024; d <<= 1) {
        int t = (tid >= d) ? buf[tid - d] : 0;
        __syncthreads();
        buf[tid] += t;
        __syncthreads();
    }
    int run = buf[tid] - s;
    #pragma unroll
    for (int i = 0; i < CH; ++i) {
        int idx = base + i;
        if (idx < NN) {
            row_ptr[idx] = run;
            cursor[idx] = run;
            run += cnt[idx];
        }
    }
    if (tid == 0) row_ptr[NN] = EE;
}

__global__ __launch_bounds__(256) void scatter_kernel(const int* __restrict__ rows,
                                                      const int* __restrict__ cols,
                                                      const float* __restrict__ vals,
                                                      int* __restrict__ cursor4,
                                                      int2* __restrict__ epair4) {
    int e = blockIdx.x * 256 + threadIdx.x;
    if (e >= EE) return;
    int k = blockIdx.y;
    size_t off = (size_t)k * EE + e;
    int r = rows[off];
    int pos = atomicAdd(&cursor4[k * NN + r], 1);
    int2 p;
    p.x = cols[off];
    p.y = __float_as_int(vals[off]);
    epair4[(size_t)k * EE + pos] = p;
}

// ---- SpMM gather: res[r] = relu(sum val*x[col]) --------------------------
__global__ __launch_bounds__(256) void gather_kernel(const float* __restrict__ x,
                                                     const int* __restrict__ row_ptr,
                                                     const int2* __restrict__ epair,
                                                     float* __restrict__ res) {
    const int tid = threadIdx.x;
    const int row = blockIdx.x * 8 + (tid >> 5);
    const int d0 = (tid & 31) * 4;
    const int start = row_ptr[row];
    const int end = row_ptr[row + 1];
    float4 a0 = make_float4(0.f, 0.f, 0.f, 0.f);
    float4 a1 = a0, a2 = a0, a3 = a0;
    int e = start;
    for (; e + 3 < end; e += 4) {
        int2 p0 = epair[e], p1 = epair[e + 1], p2 = epair[e + 2], p3 = epair[e + 3];
        float4 x0 = *reinterpret_cast<const float4*>(x + (size_t)p0.x * DD + d0);
        float4 x1 = *reinterpret_cast<const float4*>(x + (size_t)p1.x * DD + d0);
        float4 x2 = *reinterpret_cast<const float4*>(x + (size_t)p2.x * DD + d0);
        float4 x3 = *reinterpret_cast<const float4*>(x + (size_t)p3.x * DD + d0);
        float v0 = __int_as_float(p0.y), v1 = __int_as_float(p1.y);
        float v2 = __int_as_float(p2.y), v3 = __int_as_float(p3.y);
        a0.x += v0 * x0.x; a0.y += v0 * x0.y; a0.z += v0 * x0.z; a0.w += v0 * x0.w;
        a1.x += v1 * x1.x; a1.y += v1 * x1.y; a1.z += v1 * x1.z; a1.w += v1 * x1.w;
        a2.x += v2 * x2.x; a2.y += v2 * x2.y; a2.z += v2 * x2.z; a2.w += v2 * x2.w;
        a3.x += v3 * x3.x; a3.y += v3 * x3.y; a3.z += v3 * x3.z; a3.w += v3 * x3.w;
    }
    for (; e < end; ++e) {
        int2 p0 = epair[e];
        float v0 = __int_as_float(p0.y);
        float4 x0 = *reinterpret_cast<const float4*>(x + (size_t)p0.x * DD + d0);
        a0.x += v0 * x0.x; a0.y += v0 * x0.y; a0.z += v0 * x0.z; a0.w += v0 * x0.w;
    }
    float4 o;
    o.x = fmaxf((a0.x + a1.x) + (a2.x + a3.x), 0.f);
    o.y = fmaxf((a0.y + a1.y) + (a2.y + a3.y), 0.f);
    o.z = fmaxf((a0.z + a1.z) + (a2.z + a3.z), 0.f);
    o.w = fmaxf((a0.w + a1.w) + (a2.w + a3.w), 0.f);
    *reinterpret_cast<float4*>(res + (size_t)row * DD + d0) = o;
}

// ---- Fused dual-GEMM + GRU ------------------------------------------------
// Block: 64 rows (lanes) x 64 cols (16 waves x 4 j); grid.y=2 j-halves.
// h double-buffered across steps (h_in -> h_out) — no inter-block hazard.
// Weights: wave-uniform scalar loads (24 floats/k), 2-deep SGPR ping-pong.
template <bool FIRST>
__global__ __launch_bounds__(1024) void gru_step_kernel(const float* __restrict__ res,
                                                        const float* __restrict__ h_in,
                                                        float* __restrict__ h_out,
                                                        const float* __restrict__ wpk,
                                                        const float* __restrict__ bx,
                                                        const float* __restrict__ bh) {
    __shared__ float s_a[128 * 64];                 // relu(res) transposed, 32 KB
    __shared__ float s_b[FIRST ? 64 : 128 * 64];    // h transposed

    const int tid = threadIdx.x;
    const int row0 = blockIdx.x * 64;

    // stage + transpose; swizzled write s[(k<<6) | (rl ^ (k>>2))]
    #pragma unroll
    for (int p = 0; p < 2; ++p) {
        int idx = p * 1024 + tid;
        int rl = idx >> 5;
        int kq = (idx & 31) * 4;
        int grow = row0 + rl;
        float4 rv = make_float4(0.f, 0.f, 0.f, 0.f);
        float4 hv = make_float4(0.f, 0.f, 0.f, 0.f);
        if (grow < NN) {
            rv = *reinterpret_cast<const float4*>(res + (size_t)grow * DD + kq);
            if (!FIRST) hv = *reinterpret_cast<const float4*>(h_in + (size_t)grow * DD + kq);
        }
        float rr[4] = {rv.x, rv.y, rv.z, rv.w};
        float hh[4] = {hv.x, hv.y, hv.z, hv.w};
        int g = idx & 31;                  // == (kq+i)>>2 for i in 0..3
        int swb = (rl ^ g);
        #pragma unroll
        for (int i = 0; i < 4; ++i) {
            int sw = ((kq + i) << 6) | swb;
            s_a[sw] = rr[i];
            if (!FIRST) s_b[sw] = hh[i];
        }
    }

    const int lane = tid & 63;
    const int wave = __builtin_amdgcn_readfirstlane(tid >> 6);  // 0..15, uniform
    const int jg = blockIdx.y * 16 + wave;                      // 0..31, uniform
    const int jbase = jg * 4;
    const float* __restrict__ wbase = wpk + jg * 24;            // uniform base

    float sr[4], si[4], sn[4], hn[4];
    {
        float4 xr = *reinterpret_cast<const float4*>(bx + jbase);
        float4 xi = *reinterpret_cast<const float4*>(bx + DD + jbase);
        float4 xn = *reinterpret_cast<const float4*>(bx + 2 * DD + jbase);
        float4 hr = *reinterpret_cast<const float4*>(bh + jbase);
        float4 hi = *reinterpret_cast<const float4*>(bh + DD + jbase);
        float4 hq = *reinterpret_cast<const float4*>(bh + 2 * DD + jbase);
        sr[0] = xr.x + hr.x; sr[1] = xr.y + hr.y; sr[2] = xr.z + hr.z; sr[3] = xr.w + hr.w;
        si[0] = xi.x + hi.x; si[1] = xi.y + hi.y; si[2] = xi.z + hi.z; si[3] = xi.w + hi.w;
        sn[0] = xn.x; sn[1] = xn.y; sn[2] = xn.z; sn[3] = xn.w;
        hn[0] = hq.x; hn[1] = hq.y; hn[2] = hq.z; hn[3] = hq.w;
    }

    constexpr int NS = FIRST ? 12 : 24;   // uniform floats per k
    float wA[NS], wB[NS];
    #pragma unroll
    for (int t = 0; t < NS; ++t) { wA[t] = wbase[t]; wB[t] = wbase[768 + t]; }

    __syncthreads();   // the only barrier

    for (int k = 0; k < DD; k += 2) {
        int sw0 = (k << 6) | (lane ^ (k >> 2));
        float a0 = s_a[sw0];
        float a1 = s_a[sw0 + 64];
        float b0 = 0.f, b1 = 0.f;
        if (!FIRST) { b0 = s_b[sw0]; b1 = s_b[sw0 + 64]; }

        // consume wA (k), then refill for k+2 (pad k-rows 128/129 exist)
        #pragma unroll
        for (int j = 0; j < 4; ++j) {
            sr[j] += a0 * wA[j];
            si[j] += a0 * wA[4 + j];
            sn[j] += a0 * wA[8 + j];
            if (!FIRST) {
                sr[j] += b0 * wA[12 + j];
                si[j] += b0 * wA[16 + j];
                hn[j] += b0 * wA[20 + j];
            }
        }
        {
            const float* q = wbase + (size_t)(k + 2) * 768;
            #pragma unroll
            for (int t = 0; t < NS; ++t) wA[t] = q[t];
        }

        // consume wB (k+1), refill for k+3
        #pragma unroll
        for (int j = 0; j < 4; ++j) {
            sr[j] += a1 * wB[j];
            si[j] += a1 * wB[4 + j];
            sn[j] += a1 * wB[8 + j];
            if (!FIRST) {
                sr[j] += b1 * wB[12 + j];
                si[j] += b1 * wB[16 + j];
                hn[j] += b1 * wB[20 + j];
            }
        }
        {
            const float* q = wbase + (size_t)(k + 3) * 768;
            #pragma unroll
            for (int t = 0; t < NS; ++t) wB[t] = q[t];
        }
    }

    int row = row0 + lane;
    if (row < NN) {
        float o[4];
        #pragma unroll
        for (int j = 0; j < 4; ++j) {
            int jc = jbase + j;
            float ho = 0.f;
            if (!FIRST) ho = s_b[(jc << 6) | (lane ^ (jc >> 2))];
            float rg = sigmoid_f(sr[j]);
            float ig = sigmoid_f(si[j]);
            float ng = tanh_f(sn[j] + rg * hn[j]);
            o[j] = ng + ig * (ho - ng);
        }
        *reinterpret_cast<float4*>(h_out + (size_t)row * DD + jbase) =
            make_float4(o[0], o[1], o[2], o[3]);
    }
}

// LayerNorm over D=128, 32 lanes/row, two-pass variance (matches jnp.var)
__global__ __launch_bounds__(256) void ln_kernel(float* __restrict__ h,
                                                 const float* __restrict__ g,
                                                 const float* __restrict__ b) {
    int tid = threadIdx.x;
    int lane = tid & 31;
    int rl = tid >> 5;
    int row = blockIdx.x * 8 + rl;
    if (row >= NN) return;
    float4 v = *reinterpret_cast<const float4*>(h + (size_t)row * DD + lane * 4);
    float s = v.x + v.y + v.z + v.w;
    #pragma unroll
    for (int m = 16; m >= 1; m >>= 1) s += __shfl_xor(s, m, 64);
    float mean = s * (1.0f / DD);
    float dx = v.x - mean, dy = v.y - mean, dz = v.z - mean, dw = v.w - mean;
    float q = dx * dx + dy * dy + dz * dz + dw * dw;
    #pragma unroll
    for (int m = 16; m >= 1; m >>= 1) q += __shfl_xor(q, m, 64);
    float var = q * (1.0f / DD);
    float inv = 1.0f / sqrtf(var + 1e-5f);
    float4 gv = *reinterpret_cast<const float4*>(g + lane * 4);
    float4 bv = *reinterpret_cast<const float4*>(b + lane * 4);
    float4 o;
    o.x = dx * inv * gv.x + bv.x;
    o.y = dy * inv * gv.y + bv.y;
    o.z = dz * inv * gv.z + bv.z;
    o.w = dw * inv * gv.w + bv.w;
    *reinterpret_cast<float4*>(h + (size_t)row * DD + lane * 4) = o;
}

static inline size_t align_up(size_t v, size_t a) { return (v + a - 1) & ~(a - 1); }

extern "C" void kernel_launch(void* const* d_in, const int* in_sizes, int n_in,
                              void* d_out, int out_size, void* d_ws, size_t ws_size,
                              hipStream_t stream) {
    const float* x    = (const float*)d_in[0];
    const float* vals = (const float*)d_in[1];
    const float* wx   = (const float*)d_in[2];
    const float* bx   = (const float*)d_in[3];
    const float* wh   = (const float*)d_in[4];
    const float* bh   = (const float*)d_in[5];
    const float* lng  = (const float*)d_in[6];
    const float* lnb  = (const float*)d_in[7];
    const int* rows   = (const int*)d_in[8];
    const int* cols   = (const int*)d_in[9];

    float* hout = (float*)d_out;

    size_t off = 0;
    char* wsb = (char*)d_ws;
    float* res = (float*)(wsb + off);      off = align_up(off + (size_t)NN * DD * 4, 256);
    float* hbuf = (float*)(wsb + off);     off = align_up(off + (size_t)NN * DD * 4, 256);
    float* wpk = (float*)(wsb + off);      off = align_up(off + (size_t)130 * 768 * 4, 256);  // 2 pad k-rows
    int* row_ptr4 = (int*)(wsb + off);     off = align_up(off + (size_t)4 * (NN + 1) * 4, 256);
    int* cnt4 = (int*)(wsb + off);         off = align_up(off + (size_t)4 * NN * 4, 256);
    int* cursor4 = (int*)(wsb + off);      off = align_up(off + (size_t)4 * NN * 4, 256);
    int2* epair4 = (int2*)(wsb + off);     off = align_up(off + (size_t)4 * EE * 8, 256);

    (void)in_sizes; (void)n_in; (void)out_size; (void)ws_size;

    pack_w_kernel<<<384, 256, 0, stream>>>(wx, wh, wpk);

    hipMemsetAsync(cnt4, 0, (size_t)4 * NN * sizeof(int), stream);
    dim3 egrid((EE + 255) / 256, 4);
    hist_kernel<<<egrid, 256, 0, stream>>>(rows, cnt4);
    scan_kernel<<<4, 1024, 0, stream>>>(cnt4, row_ptr4, cursor4);
    scatter_kernel<<<egrid, 256, 0, stream>>>(rows, cols, vals, cursor4, epair4);

    const int ggrid = NN / 8;                      // 6250
    dim3 gru_grid((NN + 63) / 64, 2);              // 782 x 2

    // h ping-pong: s0 -> hbuf, s1 hbuf->d_out, s2 d_out->hbuf, s3 hbuf->d_out
    float* hseq_in[4]  = {nullptr, hbuf, hout, hbuf};
    float* hseq_out[4] = {hbuf,    hout, hbuf, hout};

    for (int s = 0; s < 4; ++s) {
        int k = 3 - s;  // adj_list reversed
        gather_kernel<<<ggrid, 256, 0, stream>>>(
            x, row_ptr4 + (size_t)k * (NN + 1), epair4 + (size_t)k * EE, res);
        if (s == 0)
            gru_step_kernel<true><<<gru_grid, 1024, 0, stream>>>(
                res, hseq_in[s], hseq_out[s], wpk, bx, bh);
        else
            gru_step_kernel<false><<<gru_grid, 1024, 0, stream>>>(
                res, hseq_in[s], hseq_out[s], wpk, bx, bh);
    }

    ln_kernel<<<(NN + 7) / 8, 256, 0, stream>>>(hout, lng, lnb);
}

// Round 8
// 1227.343 us; speedup vs baseline: 3.3466x; 1.0278x over previous
//
#include <hip/hip_runtime.h>
#include <cstdint>

#define NN 50000
#define DD 128
#define EE 600000

__device__ __forceinline__ float sigmoid_f(float x) {
    return 1.0f / (1.0f + __expf(-x));
}
__device__ __forceinline__ float tanh_f(float x) {
    float e = __expf(-2.0f * fabsf(x));
    float t = (1.0f - e) / (1.0f + e);
    return copysignf(t, x);
}

// ---- weight packing: wpk[k][jg(32)][gate(6)][jj(4)] ----------------------
// Per (k, jg): 24 contiguous floats (6 float4), wave-uniform.
__global__ __launch_bounds__(256) void pack_w_kernel(const float* __restrict__ wx,
                                                     const float* __restrict__ wh,
                                                     float* __restrict__ wpk) {
    int idx = blockIdx.x * 256 + threadIdx.x;
    if (idx >= 128 * 768) return;
    int k = idx / 768;
    int rem = idx - k * 768;
    int jg = rem / 24;
    int g = (rem % 24) >> 2;
    int jj = rem & 3;
    int c = jg * 4 + jj;
    float v = (g < 3) ? wx[(g * 128 + c) * 128 + k]
                      : wh[((g - 3) * 128 + c) * 128 + k];
    wpk[idx] = v;
}

// ---- CSR build (all 4 adjacencies batched) -------------------------------

__global__ __launch_bounds__(256) void hist_kernel(const int* __restrict__ rows,
                                                   int* __restrict__ cnt4) {
    int e = blockIdx.x * 256 + threadIdx.x;
    if (e >= EE) return;
    int k = blockIdx.y;
    atomicAdd(&cnt4[k * NN + rows[(size_t)k * EE + e]], 1);
}

__global__ __launch_bounds__(1024) void scan_kernel(const int* __restrict__ cnt4,
                                                    int* __restrict__ row_ptr4,
                                                    int* __restrict__ cursor4) {
    __shared__ int buf[1024];
    const int kadj = blockIdx.x;
    const int* cnt = cnt4 + kadj * NN;
    int* row_ptr = row_ptr4 + kadj * (NN + 1);
    int* cursor = cursor4 + kadj * NN;
    const int tid = threadIdx.x;
    const int CH = (NN + 1023) / 1024;  // 49
    const int base = tid * CH;
    int s = 0;
    #pragma unroll
    for (int i = 0; i < CH; ++i) {
        int idx = base + i;
        if (idx < NN) s += cnt[idx];
    }
    buf[tid] = s;
    __syncthreads();
    for (int d = 1; d < 1024; d <<= 1) {
        int t = (tid >= d) ? buf[tid - d] : 0;
        __syncthreads();
        buf[tid] += t;
        __syncthreads();
    }
    int run = buf[tid] - s;
    #pragma unroll
    for (int i = 0; i < CH; ++i) {
        int idx = base + i;
        if (idx < NN) {
            row_ptr[idx] = run;
            cursor[idx] = run;
            run += cnt[idx];
        }
    }
    if (tid == 0) row_ptr[NN] = EE;
}

__global__ __launch_bounds__(256) void scatter_kernel(const int* __restrict__ rows,
                                                      const int* __restrict__ cols,
                                                      const float* __restrict__ vals,
                                                      int* __restrict__ cursor4,
                                                      int2* __restrict__ epair4) {
    int e = blockIdx.x * 256 + threadIdx.x;
    if (e >= EE) return;
    int k = blockIdx.y;
    size_t off = (size_t)k * EE + e;
    int r = rows[off];
    int pos = atomicAdd(&cursor4[k * NN + r], 1);
    int2 p;
    p.x = cols[off];
    p.y = __float_as_int(vals[off]);
    epair4[(size_t)k * EE + pos] = p;
}

// ---- SpMM gather: res[r] = relu(sum val*x[col]) --------------------------
__global__ __launch_bounds__(256) void gather_kernel(const float* __restrict__ x,
                                                     const int* __restrict__ row_ptr,
                                                     const int2* __restrict__ epair,
                                                     float* __restrict__ res) {
    const int tid = threadIdx.x;
    const int row = blockIdx.x * 8 + (tid >> 5);
    const int d0 = (tid & 31) * 4;
    const int start = row_ptr[row];
    const int end = row_ptr[row + 1];
    float4 a0 = make_float4(0.f, 0.f, 0.f, 0.f);
    float4 a1 = a0, a2 = a0, a3 = a0;
    int e = start;
    for (; e + 3 < end; e += 4) {
        int2 p0 = epair[e], p1 = epair[e + 1], p2 = epair[e + 2], p3 = epair[e + 3];
        float4 x0 = *reinterpret_cast<const float4*>(x + (size_t)p0.x * DD + d0);
        float4 x1 = *reinterpret_cast<const float4*>(x + (size_t)p1.x * DD + d0);
        float4 x2 = *reinterpret_cast<const float4*>(x + (size_t)p2.x * DD + d0);
        float4 x3 = *reinterpret_cast<const float4*>(x + (size_t)p3.x * DD + d0);
        float v0 = __int_as_float(p0.y), v1 = __int_as_float(p1.y);
        float v2 = __int_as_float(p2.y), v3 = __int_as_float(p3.y);
        a0.x += v0 * x0.x; a0.y += v0 * x0.y; a0.z += v0 * x0.z; a0.w += v0 * x0.w;
        a1.x += v1 * x1.x; a1.y += v1 * x1.y; a1.z += v1 * x1.z; a1.w += v1 * x1.w;
        a2.x += v2 * x2.x; a2.y += v2 * x2.y; a2.z += v2 * x2.z; a2.w += v2 * x2.w;
        a3.x += v3 * x3.x; a3.y += v3 * x3.y; a3.z += v3 * x3.z; a3.w += v3 * x3.w;
    }
    for (; e < end; ++e) {
        int2 p0 = epair[e];
        float v0 = __int_as_float(p0.y);
        float4 x0 = *reinterpret_cast<const float4*>(x + (size_t)p0.x * DD + d0);
        a0.x += v0 * x0.x; a0.y += v0 * x0.y; a0.z += v0 * x0.z; a0.w += v0 * x0.w;
    }
    float4 o;
    o.x = fmaxf((a0.x + a1.x) + (a2.x + a3.x), 0.f);
    o.y = fmaxf((a0.y + a1.y) + (a2.y + a3.y), 0.f);
    o.z = fmaxf((a0.z + a1.z) + (a2.z + a3.z), 0.f);
    o.w = fmaxf((a0.w + a1.w) + (a2.w + a3.w), 0.f);
    *reinterpret_cast<float4*>(res + (size_t)row * DD + d0) = o;
}

// ---- Fused dual-GEMM + GRU ------------------------------------------------
// Block: 64 rows (lanes) x 64 cols (16 waves x 4 j); grid.y=2 j-halves.
// h double-buffered across steps (h_in -> h_out) — no inter-block hazard.
// Weights: wave-uniform VMEM float4 loads (vmcnt pipe — no lgkm mixing with
// the ds_reads), depth-2 VGPR ping-pong (6 float4 per k).
#define FMA4(acc, s, q)                                                   \
    acc[0] += s * q.x; acc[1] += s * q.y; acc[2] += s * q.z; acc[3] += s * q.w;

template <bool FIRST>
__global__ __launch_bounds__(1024, 1) void gru_step_kernel(const float* __restrict__ res,
                                                           const float* __restrict__ h_in,
                                                           float* __restrict__ h_out,
                                                           const float* __restrict__ wpk,
                                                           const float* __restrict__ bx,
                                                           const float* __restrict__ bh) {
    __shared__ float s_a[128 * 64];                 // relu(res) transposed, 32 KB
    __shared__ float s_b[FIRST ? 64 : 128 * 64];    // h transposed

    const int tid = threadIdx.x;
    const int row0 = blockIdx.x * 64;

    // stage + transpose; swizzled write s[(k<<6) | (rl ^ (k>>2))]
    #pragma unroll
    for (int p = 0; p < 2; ++p) {
        int idx = p * 1024 + tid;
        int rl = idx >> 5;
        int kq = (idx & 31) * 4;
        int grow = row0 + rl;
        float4 rv = make_float4(0.f, 0.f, 0.f, 0.f);
        float4 hv = make_float4(0.f, 0.f, 0.f, 0.f);
        if (grow < NN) {
            rv = *reinterpret_cast<const float4*>(res + (size_t)grow * DD + kq);
            if (!FIRST) hv = *reinterpret_cast<const float4*>(h_in + (size_t)grow * DD + kq);
        }
        float rr[4] = {rv.x, rv.y, rv.z, rv.w};
        float hh[4] = {hv.x, hv.y, hv.z, hv.w};
        int g = idx & 31;                  // == (kq+i)>>2 for i in 0..3
        int swb = (rl ^ g);
        #pragma unroll
        for (int i = 0; i < 4; ++i) {
            int sw = ((kq + i) << 6) | swb;
            s_a[sw] = rr[i];
            if (!FIRST) s_b[sw] = hh[i];
        }
    }

    const int lane = tid & 63;
    const int wave = __builtin_amdgcn_readfirstlane(tid >> 6);  // 0..15, uniform
    const int jg = blockIdx.y * 16 + wave;                      // 0..31, uniform
    const int jbase = jg * 4;
    const float* __restrict__ wbase = wpk + jg * 24;            // uniform base

    float sr[4], si[4], sn[4], hn[4];
    {
        float4 xr = *reinterpret_cast<const float4*>(bx + jbase);
        float4 xi = *reinterpret_cast<const float4*>(bx + DD + jbase);
        float4 xn = *reinterpret_cast<const float4*>(bx + 2 * DD + jbase);
        float4 hr = *reinterpret_cast<const float4*>(bh + jbase);
        float4 hi = *reinterpret_cast<const float4*>(bh + DD + jbase);
        float4 hq = *reinterpret_cast<const float4*>(bh + 2 * DD + jbase);
        sr[0] = xr.x + hr.x; sr[1] = xr.y + hr.y; sr[2] = xr.z + hr.z; sr[3] = xr.w + hr.w;
        si[0] = xi.x + hi.x; si[1] = xi.y + hi.y; si[2] = xi.z + hi.z; si[3] = xi.w + hi.w;
        sn[0] = xn.x; sn[1] = xn.y; sn[2] = xn.z; sn[3] = xn.w;
        hn[0] = hq.x; hn[1] = hq.y; hn[2] = hq.z; hn[3] = hq.w;
    }

    constexpr int NQ = FIRST ? 3 : 6;   // float4s of weights per k
    float4 wA[NQ], wB[NQ];
    {
        const float4* q0 = reinterpret_cast<const float4*>(wbase);
        const float4* q1 = reinterpret_cast<const float4*>(wbase + 768);
        #pragma unroll
        for (int t = 0; t < NQ; ++t) { wA[t] = q0[t]; wB[t] = q1[t]; }
    }

    __syncthreads();   // the only barrier

    for (int k = 0; k < DD; k += 2) {
        int sw0 = (k << 6) | (lane ^ (k >> 2));
        float a0 = s_a[sw0];
        float a1 = s_a[sw0 + 64];
        float b0 = 0.f, b1 = 0.f;
        if (!FIRST) { b0 = s_b[sw0]; b1 = s_b[sw0 + 64]; }

        // consume wA (k), then refill for k+2 (pad k-rows 128/129 exist)
        FMA4(sr, a0, wA[0]);
        FMA4(si, a0, wA[1]);
        FMA4(sn, a0, wA[2]);
        if (!FIRST) {
            FMA4(sr, b0, wA[3]);
            FMA4(si, b0, wA[4]);
            FMA4(hn, b0, wA[5]);
        }
        {
            const float4* q = reinterpret_cast<const float4*>(wbase + (size_t)(k + 2) * 768);
            #pragma unroll
            for (int t = 0; t < NQ; ++t) wA[t] = q[t];
        }

        // consume wB (k+1), refill for k+3
        FMA4(sr, a1, wB[0]);
        FMA4(si, a1, wB[1]);
        FMA4(sn, a1, wB[2]);
        if (!FIRST) {
            FMA4(sr, b1, wB[3]);
            FMA4(si, b1, wB[4]);
            FMA4(hn, b1, wB[5]);
        }
        {
            const float4* q = reinterpret_cast<const float4*>(wbase + (size_t)(k + 3) * 768);
            #pragma unroll
            for (int t = 0; t < NQ; ++t) wB[t] = q[t];
        }
    }

    int row = row0 + lane;
    if (row < NN) {
        float o[4];
        #pragma unroll
        for (int j = 0; j < 4; ++j) {
            int jc = jbase + j;
            float ho = 0.f;
            if (!FIRST) ho = s_b[(jc << 6) | (lane ^ (jc >> 2))];
            float rg = sigmoid_f(sr[j]);
            float ig = sigmoid_f(si[j]);
            float ng = tanh_f(sn[j] + rg * hn[j]);
            o[j] = ng + ig * (ho - ng);
        }
        *reinterpret_cast<float4*>(h_out + (size_t)row * DD + jbase) =
            make_float4(o[0], o[1], o[2], o[3]);
    }
}

// LayerNorm over D=128, 32 lanes/row, two-pass variance (matches jnp.var)
__global__ __launch_bounds__(256) void ln_kernel(float* __restrict__ h,
                                                 const float* __restrict__ g,
                                                 const float* __restrict__ b) {
    int tid = threadIdx.x;
    int lane = tid & 31;
    int rl = tid >> 5;
    int row = blockIdx.x * 8 + rl;
    if (row >= NN) return;
    float4 v = *reinterpret_cast<const float4*>(h + (size_t)row * DD + lane * 4);
    float s = v.x + v.y + v.z + v.w;
    #pragma unroll
    for (int m = 16; m >= 1; m >>= 1) s += __shfl_xor(s, m, 64);
    float mean = s * (1.0f / DD);
    float dx = v.x - mean, dy = v.y - mean, dz = v.z - mean, dw = v.w - mean;
    float q = dx * dx + dy * dy + dz * dz + dw * dw;
    #pragma unroll
    for (int m = 16; m >= 1; m >>= 1) q += __shfl_xor(q, m, 64);
    float var = q * (1.0f / DD);
    float inv = 1.0f / sqrtf(var + 1e-5f);
    float4 gv = *reinterpret_cast<const float4*>(g + lane * 4);
    float4 bv = *reinterpret_cast<const float4*>(b + lane * 4);
    float4 o;
    o.x = dx * inv * gv.x + bv.x;
    o.y = dy * inv * gv.y + bv.y;
    o.z = dz * inv * gv.z + bv.z;
    o.w = dw * inv * gv.w + bv.w;
    *reinterpret_cast<float4*>(h + (size_t)row * DD + lane * 4) = o;
}

static inline size_t align_up(size_t v, size_t a) { return (v + a - 1) & ~(a - 1); }

extern "C" void kernel_launch(void* const* d_in, const int* in_sizes, int n_in,
                              void* d_out, int out_size, void* d_ws, size_t ws_size,
                              hipStream_t stream) {
    const float* x    = (const float*)d_in[0];
    const float* vals = (const float*)d_in[1];
    const float* wx   = (const float*)d_in[2];
    const float* bx   = (const float*)d_in[3];
    const float* wh   = (const float*)d_in[4];
    const float* bh   = (const float*)d_in[5];
    const float* lng  = (const float*)d_in[6];
    const float* lnb  = (const float*)d_in[7];
    const int* rows   = (const int*)d_in[8];
    const int* cols   = (const int*)d_in[9];

    float* hout = (float*)d_out;

    size_t off = 0;
    char* wsb = (char*)d_ws;
    float* res = (float*)(wsb + off);      off = align_up(off + (size_t)NN * DD * 4, 256);
    float* hbuf = (float*)(wsb + off);     off = align_up(off + (size_t)NN * DD * 4, 256);
    float* wpk = (float*)(wsb + off);      off = align_up(off + (size_t)130 * 768 * 4, 256);  // 2 pad k-rows
    int* row_ptr4 = (int*)(wsb + off);     off = align_up(off + (size_t)4 * (NN + 1) * 4, 256);
    int* cnt4 = (int*)(wsb + off);         off = align_up(off + (size_t)4 * NN * 4, 256);
    int* cursor4 = (int*)(wsb + off);      off = align_up(off + (size_t)4 * NN * 4, 256);
    int2* epair4 = (int2*)(wsb + off);     off = align_up(off + (size_t)4 * EE * 8, 256);

    (void)in_sizes; (void)n_in; (void)out_size; (void)ws_size;

    pack_w_kernel<<<384, 256, 0, stream>>>(wx, wh, wpk);

    hipMemsetAsync(cnt4, 0, (size_t)4 * NN * sizeof(int), stream);
    dim3 egrid((EE + 255) / 256, 4);
    hist_kernel<<<egrid, 256, 0, stream>>>(rows, cnt4);
    scan_kernel<<<4, 1024, 0, stream>>>(cnt4, row_ptr4, cursor4);
    scatter_kernel<<<egrid, 256, 0, stream>>>(rows, cols, vals, cursor4, epair4);

    const int ggrid = NN / 8;                      // 6250
    dim3 gru_grid((NN + 63) / 64, 2);              // 782 x 2

    // h ping-pong: s0 -> hbuf, s1 hbuf->d_out, s2 d_out->hbuf, s3 hbuf->d_out
    float* hseq_in[4]  = {nullptr, hbuf, hout, hbuf};
    float* hseq_out[4] = {hbuf,    hout, hbuf, hout};

    for (int s = 0; s < 4; ++s) {
        int k = 3 - s;  // adj_list reversed
        gather_kernel<<<ggrid, 256, 0, stream>>>(
            x, row_ptr4 + (size_t)k * (NN + 1), epair4 + (size_t)k * EE, res);
        if (s == 0)
            gru_step_kernel<true><<<gru_grid, 1024, 0, stream>>>(
                res, hseq_in[s], hseq_out[s], wpk, bx, bh);
        else
            gru_step_kernel<false><<<gru_grid, 1024, 0, stream>>>(
                res, hseq_in[s], hseq_out[s], wpk, bx, bh);
    }

    ln_kernel<<<(NN + 7) / 8, 256, 0, stream>>>(hout, lng, lnb);
}

// Round 9
// 1217.878 us; speedup vs baseline: 3.3726x; 1.0078x over previous
//
#include <hip/hip_runtime.h>
#include <cstdint>

#define NN 50000
#define DD 128
#define EE 600000

__device__ __forceinline__ float sigmoid_f(float x) {
    return 1.0f / (1.0f + __expf(-x));
}
__device__ __forceinline__ float tanh_f(float x) {
    float e = __expf(-2.0f * fabsf(x));
    float t = (1.0f - e) / (1.0f + e);
    return copysignf(t, x);
}

// ---- weight packing: wpk[k][jg(32)][32pad] -------------------------------
// Per (k, jg): 24 used floats (6 gates x 4 j), wave-uniform, 128B-aligned.
__global__ __launch_bounds__(256) void pack_w_kernel(const float* __restrict__ wx,
                                                     const float* __restrict__ wh,
                                                     float* __restrict__ wpk) {
    int idx = blockIdx.x * 256 + threadIdx.x;
    if (idx >= 128 * 1024) return;
    int k = idx >> 10;
    int rem = idx & 1023;
    int jg = rem >> 5;
    int t = rem & 31;
    float v = 0.f;
    if (t < 24) {
        int g = t >> 2;
        int jj = t & 3;
        int c = jg * 4 + jj;
        v = (g < 3) ? wx[(g * 128 + c) * 128 + k]
                    : wh[((g - 3) * 128 + c) * 128 + k];
    }
    wpk[idx] = v;
}

// ---- CSR build (all 4 adjacencies batched) -------------------------------

__global__ __launch_bounds__(256) void hist_kernel(const int* __restrict__ rows,
                                                   int* __restrict__ cnt4) {
    int e = blockIdx.x * 256 + threadIdx.x;
    if (e >= EE) return;
    int k = blockIdx.y;
    atomicAdd(&cnt4[k * NN + rows[(size_t)k * EE + e]], 1);
}

__global__ __launch_bounds__(1024) void scan_kernel(const int* __restrict__ cnt4,
                                                    int* __restrict__ row_ptr4,
                                                    int* __restrict__ cursor4) {
    __shared__ int buf[1024];
    const int kadj = blockIdx.x;
    const int* cnt = cnt4 + kadj * NN;
    int* row_ptr = row_ptr4 + kadj * (NN + 1);
    int* cursor = cursor4 + kadj * NN;
    const int tid = threadIdx.x;
    const int CH = (NN + 1023) / 1024;  // 49
    const int base = tid * CH;
    int s = 0;
    #pragma unroll
    for (int i = 0; i < CH; ++i) {
        int idx = base + i;
        if (idx < NN) s += cnt[idx];
    }
    buf[tid] = s;
    __syncthreads();
    for (int d = 1; d < 1024; d <<= 1) {
        int t = (tid >= d) ? buf[tid - d] : 0;
        __syncthreads();
        buf[tid] += t;
        __syncthreads();
    }
    int run = buf[tid] - s;
    #pragma unroll
    for (int i = 0; i < CH; ++i) {
        int idx = base + i;
        if (idx < NN) {
            row_ptr[idx] = run;
            cursor[idx] = run;
            run += cnt[idx];
        }
    }
    if (tid == 0) row_ptr[NN] = EE;
}

__global__ __launch_bounds__(256) void scatter_kernel(const int* __restrict__ rows,
                                                      const int* __restrict__ cols,
                                                      const float* __restrict__ vals,
                                                      int* __restrict__ cursor4,
                                                      int2* __restrict__ epair4) {
    int e = blockIdx.x * 256 + threadIdx.x;
    if (e >= EE) return;
    int k = blockIdx.y;
    size_t off = (size_t)k * EE + e;
    int r = rows[off];
    int pos = atomicAdd(&cursor4[k * NN + r], 1);
    int2 p;
    p.x = cols[off];
    p.y = __float_as_int(vals[off]);
    epair4[(size_t)k * EE + pos] = p;
}

// ---- SpMM gather: res[r] = relu(sum val*x[col]) --------------------------
__global__ __launch_bounds__(256) void gather_kernel(const float* __restrict__ x,
                                                     const int* __restrict__ row_ptr,
                                                     const int2* __restrict__ epair,
                                                     float* __restrict__ res) {
    const int tid = threadIdx.x;
    const int row = blockIdx.x * 8 + (tid >> 5);
    const int d0 = (tid & 31) * 4;
    const int start = row_ptr[row];
    const int end = row_ptr[row + 1];
    float4 a0 = make_float4(0.f, 0.f, 0.f, 0.f);
    float4 a1 = a0, a2 = a0, a3 = a0;
    int e = start;
    for (; e + 3 < end; e += 4) {
        int2 p0 = epair[e], p1 = epair[e + 1], p2 = epair[e + 2], p3 = epair[e + 3];
        float4 x0 = *reinterpret_cast<const float4*>(x + (size_t)p0.x * DD + d0);
        float4 x1 = *reinterpret_cast<const float4*>(x + (size_t)p1.x * DD + d0);
        float4 x2 = *reinterpret_cast<const float4*>(x + (size_t)p2.x * DD + d0);
        float4 x3 = *reinterpret_cast<const float4*>(x + (size_t)p3.x * DD + d0);
        float v0 = __int_as_float(p0.y), v1 = __int_as_float(p1.y);
        float v2 = __int_as_float(p2.y), v3 = __int_as_float(p3.y);
        a0.x += v0 * x0.x; a0.y += v0 * x0.y; a0.z += v0 * x0.z; a0.w += v0 * x0.w;
        a1.x += v1 * x1.x; a1.y += v1 * x1.y; a1.z += v1 * x1.z; a1.w += v1 * x1.w;
        a2.x += v2 * x2.x; a2.y += v2 * x2.y; a2.z += v2 * x2.z; a2.w += v2 * x2.w;
        a3.x += v3 * x3.x; a3.y += v3 * x3.y; a3.z += v3 * x3.z; a3.w += v3 * x3.w;
    }
    for (; e < end; ++e) {
        int2 p0 = epair[e];
        float v0 = __int_as_float(p0.y);
        float4 x0 = *reinterpret_cast<const float4*>(x + (size_t)p0.x * DD + d0);
        a0.x += v0 * x0.x; a0.y += v0 * x0.y; a0.z += v0 * x0.z; a0.w += v0 * x0.w;
    }
    float4 o;
    o.x = fmaxf((a0.x + a1.x) + (a2.x + a3.x), 0.f);
    o.y = fmaxf((a0.y + a1.y) + (a2.y + a3.y), 0.f);
    o.z = fmaxf((a0.z + a1.z) + (a2.z + a3.z), 0.f);
    o.w = fmaxf((a0.w + a1.w) + (a2.w + a3.w), 0.f);
    *reinterpret_cast<float4*>(res + (size_t)row * DD + d0) = o;
}

// ---- Fused dual-GEMM + GRU ------------------------------------------------
// Block: 128 rows x 64 cols (16 waves x 4 j); grid.y=2 j-halves. Lane owns
// rows (l, l+64). LDS paired layout: plane k, float2 element (row&63)^((k>>2)&31)
// holds rows (m, m+64) -> ONE ds_read_b64 per array per k; coalesced h stores.
// Weights: wave-uniform (compiler -> s_load), 2-deep ping-pong, 48 FMA/k/wave.
template <bool FIRST>
__global__ __launch_bounds__(1024, FIRST ? 8 : 4)
void gru_step_kernel(const float* __restrict__ res,
                     const float* __restrict__ h_in,
                     float* __restrict__ h_out,
                     const float* __restrict__ wpk,
                     const float* __restrict__ bx,
                     const float* __restrict__ bh) {
    __shared__ float s_a[128 * 128];                 // res transposed-paired, 64 KB
    __shared__ float s_b[FIRST ? 64 : 128 * 128];    // h transposed-paired

    const int tid = threadIdx.x;
    const int row0 = blockIdx.x * 128;

    // stage: thread -> (row rl, k-quad kq); write paired-swizzled planes
    #pragma unroll
    for (int p = 0; p < 4; ++p) {
        int idx = p * 1024 + tid;          // 0..4095
        int rl = idx >> 5;                 // 0..127
        int kq = (idx & 31) * 4;
        int grow = row0 + rl;
        float4 rv = make_float4(0.f, 0.f, 0.f, 0.f);
        float4 hv = make_float4(0.f, 0.f, 0.f, 0.f);
        if (grow < NN) {
            rv = *reinterpret_cast<const float4*>(res + (size_t)grow * DD + kq);
            if (!FIRST) hv = *reinterpret_cast<const float4*>(h_in + (size_t)grow * DD + kq);
        }
        float rr[4] = {rv.x, rv.y, rv.z, rv.w};
        float hh[4] = {hv.x, hv.y, hv.z, hv.w};
        int c = idx & 31;                  // == ((kq+i)>>2)&31 for i in 0..3
        int ebase = (((rl & 63) ^ c) << 1) + (rl >> 6);
        #pragma unroll
        for (int i = 0; i < 4; ++i) {
            int w = ((kq + i) << 7) + ebase;
            s_a[w] = rr[i];
            if (!FIRST) s_b[w] = hh[i];
        }
    }

    const int lane = tid & 63;
    const int wave = __builtin_amdgcn_readfirstlane(tid >> 6);  // 0..15, uniform
    const int jg = blockIdx.y * 16 + wave;                      // 0..31, uniform
    const int jbase = jg * 4;
    const float* __restrict__ wbase = wpk + (size_t)jg * 32;    // uniform base

    // acc[r][j], r=0 -> row lane, r=1 -> row lane+64
    float sr[2][4], si[2][4], sn[2][4], hn[2][4];
    {
        float4 xr = *reinterpret_cast<const float4*>(bx + jbase);
        float4 xi = *reinterpret_cast<const float4*>(bx + DD + jbase);
        float4 xn = *reinterpret_cast<const float4*>(bx + 2 * DD + jbase);
        float4 hr = *reinterpret_cast<const float4*>(bh + jbase);
        float4 hi = *reinterpret_cast<const float4*>(bh + DD + jbase);
        float4 hq = *reinterpret_cast<const float4*>(bh + 2 * DD + jbase);
        #pragma unroll
        for (int r = 0; r < 2; ++r) {
            sr[r][0] = xr.x + hr.x; sr[r][1] = xr.y + hr.y;
            sr[r][2] = xr.z + hr.z; sr[r][3] = xr.w + hr.w;
            si[r][0] = xi.x + hi.x; si[r][1] = xi.y + hi.y;
            si[r][2] = xi.z + hi.z; si[r][3] = xi.w + hi.w;
            sn[r][0] = xn.x; sn[r][1] = xn.y; sn[r][2] = xn.z; sn[r][3] = xn.w;
            hn[r][0] = hq.x; hn[r][1] = hq.y; hn[r][2] = hq.z; hn[r][3] = hq.w;
        }
    }

    constexpr int NS = FIRST ? 12 : 24;   // uniform weight floats per k
    float wA[NS], wB[NS];
    #pragma unroll
    for (int t = 0; t < NS; ++t) { wA[t] = wbase[t]; wB[t] = wbase[1024 + t]; }

    __syncthreads();   // the only barrier

    for (int k = 0; k < DD; k += 2) {
        // c identical for k (even) and k+1
        int e = ((lane ^ ((k >> 2) & 31)) << 1);
        float2 av0 = *reinterpret_cast<const float2*>(&s_a[(k << 7) + e]);
        float2 av1 = *reinterpret_cast<const float2*>(&s_a[((k + 1) << 7) + e]);
        float2 bv0 = make_float2(0.f, 0.f), bv1 = bv0;
        if (!FIRST) {
            bv0 = *reinterpret_cast<const float2*>(&s_b[(k << 7) + e]);
            bv1 = *reinterpret_cast<const float2*>(&s_b[((k + 1) << 7) + e]);
        }

        // consume wA (k), refill for k+2 (pad k-rows exist)
        #pragma unroll
        for (int j = 0; j < 4; ++j) {
            sr[0][j] += av0.x * wA[j];     sr[1][j] += av0.y * wA[j];
            si[0][j] += av0.x * wA[4 + j]; si[1][j] += av0.y * wA[4 + j];
            sn[0][j] += av0.x * wA[8 + j]; sn[1][j] += av0.y * wA[8 + j];
            if (!FIRST) {
                sr[0][j] += bv0.x * wA[12 + j]; sr[1][j] += bv0.y * wA[12 + j];
                si[0][j] += bv0.x * wA[16 + j]; si[1][j] += bv0.y * wA[16 + j];
                hn[0][j] += bv0.x * wA[20 + j]; hn[1][j] += bv0.y * wA[20 + j];
            }
        }
        {
            const float* q = wbase + (size_t)(k + 2) * 1024;
            #pragma unroll
            for (int t = 0; t < NS; ++t) wA[t] = q[t];
        }

        // consume wB (k+1), refill for k+3
        #pragma unroll
        for (int j = 0; j < 4; ++j) {
            sr[0][j] += av1.x * wB[j];     sr[1][j] += av1.y * wB[j];
            si[0][j] += av1.x * wB[4 + j]; si[1][j] += av1.y * wB[4 + j];
            sn[0][j] += av1.x * wB[8 + j]; sn[1][j] += av1.y * wB[8 + j];
            if (!FIRST) {
                sr[0][j] += bv1.x * wB[12 + j]; sr[1][j] += bv1.y * wB[12 + j];
                si[0][j] += bv1.x * wB[16 + j]; si[1][j] += bv1.y * wB[16 + j];
                hn[0][j] += bv1.x * wB[20 + j]; hn[1][j] += bv1.y * wB[20 + j];
            }
        }
        {
            const float* q = wbase + (size_t)(k + 3) * 1024;
            #pragma unroll
            for (int t = 0; t < NS; ++t) wB[t] = q[t];
        }
    }

    #pragma unroll
    for (int r = 0; r < 2; ++r) {
        int row = row0 + lane + r * 64;
        if (row < NN) {
            float o[4];
            #pragma unroll
            for (int j = 0; j < 4; ++j) {
                float ho = 0.f;
                if (!FIRST) {
                    // jc = jbase+j -> (jc>>2)&31 == jg for j<4
                    ho = s_b[((jbase + j) << 7) + ((lane ^ jg) << 1) + r];
                }
                float rg = sigmoid_f(sr[r][j]);
                float ig = sigmoid_f(si[r][j]);
                float ng = tanh_f(sn[r][j] + rg * hn[r][j]);
                o[j] = ng + ig * (ho - ng);
            }
            *reinterpret_cast<float4*>(h_out + (size_t)row * DD + jbase) =
                make_float4(o[0], o[1], o[2], o[3]);
        }
    }
}

// LayerNorm over D=128, 32 lanes/row, two-pass variance (matches jnp.var)
__global__ __launch_bounds__(256) void ln_kernel(float* __restrict__ h,
                                                 const float* __restrict__ g,
                                                 const float* __restrict__ b) {
    int tid = threadIdx.x;
    int lane = tid & 31;
    int rl = tid >> 5;
    int row = blockIdx.x * 8 + rl;
    if (row >= NN) return;
    float4 v = *reinterpret_cast<const float4*>(h + (size_t)row * DD + lane * 4);
    float s = v.x + v.y + v.z + v.w;
    #pragma unroll
    for (int m = 16; m >= 1; m >>= 1) s += __shfl_xor(s, m, 64);
    float mean = s * (1.0f / DD);
    float dx = v.x - mean, dy = v.y - mean, dz = v.z - mean, dw = v.w - mean;
    float q = dx * dx + dy * dy + dz * dz + dw * dw;
    #pragma unroll
    for (int m = 16; m >= 1; m >>= 1) q += __shfl_xor(q, m, 64);
    float var = q * (1.0f / DD);
    float inv = 1.0f / sqrtf(var + 1e-5f);
    float4 gv = *reinterpret_cast<const float4*>(g + lane * 4);
    float4 bv = *reinterpret_cast<const float4*>(b + lane * 4);
    float4 o;
    o.x = dx * inv * gv.x + bv.x;
    o.y = dy * inv * gv.y + bv.y;
    o.z = dz * inv * gv.z + bv.z;
    o.w = dw * inv * gv.w + bv.w;
    *reinterpret_cast<float4*>(h + (size_t)row * DD + lane * 4) = o;
}

static inline size_t align_up(size_t v, size_t a) { return (v + a - 1) & ~(a - 1); }

extern "C" void kernel_launch(void* const* d_in, const int* in_sizes, int n_in,
                              void* d_out, int out_size, void* d_ws, size_t ws_size,
                              hipStream_t stream) {
    const float* x    = (const float*)d_in[0];
    const float* vals = (const float*)d_in[1];
    const float* wx   = (const float*)d_in[2];
    const float* bx   = (const float*)d_in[3];
    const float* wh   = (const float*)d_in[4];
    const float* bh   = (const float*)d_in[5];
    const float* lng  = (const float*)d_in[6];
    const float* lnb  = (const float*)d_in[7];
    const int* rows   = (const int*)d_in[8];
    const int* cols   = (const int*)d_in[9];

    float* hout = (float*)d_out;

    size_t off = 0;
    char* wsb = (char*)d_ws;
    float* res = (float*)(wsb + off);      off = align_up(off + (size_t)NN * DD * 4, 256);
    float* hbuf = (float*)(wsb + off);     off = align_up(off + (size_t)NN * DD * 4, 256);
    float* wpk = (float*)(wsb + off);      off = align_up(off + (size_t)132 * 1024 * 4, 256); // 4 pad k-rows
    int* row_ptr4 = (int*)(wsb + off);     off = align_up(off + (size_t)4 * (NN + 1) * 4, 256);
    int* cnt4 = (int*)(wsb + off);         off = align_up(off + (size_t)4 * NN * 4, 256);
    int* cursor4 = (int*)(wsb + off);      off = align_up(off + (size_t)4 * NN * 4, 256);
    int2* epair4 = (int2*)(wsb + off);     off = align_up(off + (size_t)4 * EE * 8, 256);

    (void)in_sizes; (void)n_in; (void)out_size; (void)ws_size;

    pack_w_kernel<<<512, 256, 0, stream>>>(wx, wh, wpk);

    hipMemsetAsync(cnt4, 0, (size_t)4 * NN * sizeof(int), stream);
    dim3 egrid((EE + 255) / 256, 4);
    hist_kernel<<<egrid, 256, 0, stream>>>(rows, cnt4);
    scan_kernel<<<4, 1024, 0, stream>>>(cnt4, row_ptr4, cursor4);
    scatter_kernel<<<egrid, 256, 0, stream>>>(rows, cols, vals, cursor4, epair4);

    const int ggrid = NN / 8;                      // 6250
    dim3 gru_grid((NN + 127) / 128, 2);            // 391 x 2

    // h ping-pong: s0 -> hbuf, s1 hbuf->d_out, s2 d_out->hbuf, s3 hbuf->d_out
    float* hseq_in[4]  = {nullptr, hbuf, hout, hbuf};
    float* hseq_out[4] = {hbuf,    hout, hbuf, hout};

    for (int s = 0; s < 4; ++s) {
        int k = 3 - s;  // adj_list reversed
        gather_kernel<<<ggrid, 256, 0, stream>>>(
            x, row_ptr4 + (size_t)k * (NN + 1), epair4 + (size_t)k * EE, res);
        if (s == 0)
            gru_step_kernel<true><<<gru_grid, 1024, 0, stream>>>(
                res, hseq_in[s], hseq_out[s], wpk, bx, bh);
        else
            gru_step_kernel<false><<<gru_grid, 1024, 0, stream>>>(
                res, hseq_in[s], hseq_out[s], wpk, bx, bh);
    }

    ln_kernel<<<(NN + 7) / 8, 256, 0, stream>>>(hout, lng, lnb);
}